// Round 4
// baseline (605.391 us; speedup 1.0000x reference)
//
#include <hip/hip_runtime.h>
#include <stdint.h>

// out = x @ (W + 2*L@R)^T + b,  x[8192,4096] fp32, W[4096,4096] fp32.
//   out = x@W^T + (2*(x@R^T))@L^T + b
//   prep2: x->bf16, W->bf16, y1b = [2*(x@R^T)|0] bf16   (one kernel)
//   gemm8: 128x256-tile BK=32 bf16 MFMA GEMM, 2 WGs/CU (VGPR<=128, LDS 48KB)
//          -> cross-WG MFMA/LDS pipe overlap; + K=32 LoRA peel + bias.
#define NTOK     8192
#define D_OUT    4096
#define D_IN     4096
#define LORA_DIM 16

typedef short  short8  __attribute__((ext_vector_type(8)));
typedef float  floatx4 __attribute__((ext_vector_type(4)));
typedef unsigned short ushort8 __attribute__((ext_vector_type(8)));

typedef unsigned int u32;
typedef __attribute__((address_space(3))) u32 lds_u32;
typedef __attribute__((address_space(1))) u32 glb_u32;

__device__ __forceinline__ unsigned short f2bf(float f) {
  unsigned int u = __builtin_bit_cast(unsigned int, f);
  u += 0x7FFFu + ((u >> 16) & 1u);
  return (unsigned short)(u >> 16);
}

__device__ __forceinline__ void copy16(const void* g, void* l) {
  __builtin_amdgcn_global_load_lds((glb_u32*)(uintptr_t)g, (lds_u32*)(uintptr_t)l,
                                   16, 0, 0);
}

__device__ __forceinline__ void cvt8(const float* __restrict__ s,
                                     unsigned short* __restrict__ d) {
  const float4 a = *(const float4*)s;
  const float4 b = *(const float4*)(s + 4);
  ushort8 o;
  o[0] = f2bf(a.x); o[1] = f2bf(a.y); o[2] = f2bf(a.z); o[3] = f2bf(a.w);
  o[4] = f2bf(b.x); o[5] = f2bf(b.y); o[6] = f2bf(b.z); o[7] = f2bf(b.w);
  *(ushort8*)d = o;
}

__device__ __forceinline__ short8 cvt8r(const float* __restrict__ s) {
  const float4 a = *(const float4*)s;
  const float4 b = *(const float4*)(s + 4);
  short8 o;
  o[0] = (short)f2bf(a.x); o[1] = (short)f2bf(a.y);
  o[2] = (short)f2bf(a.z); o[3] = (short)f2bf(a.w);
  o[4] = (short)f2bf(b.x); o[5] = (short)f2bf(b.y);
  o[6] = (short)f2bf(b.z); o[7] = (short)f2bf(b.w);
  return o;
}

// ---------------------------------------------------------------------------
// prep2: 512 blocks x 256. Block b:
//   (1) cast x rows 16b..16b+16 -> xb
//   (2) cast W rows 8b..8b+8 -> wb
//   (3) y1 = 2*(x@R^T) for rows 16b..16b+16 (4 waves split K; x,R read fp32
//       with in-register cvt -> no dependency on (1), no fence needed)
// ---------------------------------------------------------------------------
__global__ __launch_bounds__(256) void prep2(const float* __restrict__ X,
                                             const float* __restrict__ W,
                                             const float* __restrict__ R,
                                             unsigned short* __restrict__ xb,
                                             unsigned short* __restrict__ wb,
                                             unsigned short* __restrict__ y1b) {
  __shared__ float red[4][256];
  const int b = blockIdx.x;
  const int tid = threadIdx.x;
  const int mb = b * 16;

  // (1) x cast: 16 rows, 16 elems/thread/row
#pragma unroll 4
  for (int r = 0; r < 16; ++r) {
    const size_t off = (size_t)(mb + r) * D_IN + tid * 16;
    cvt8(X + off, xb + off);
    cvt8(X + off + 8, xb + off + 8);
  }
  // (2) W cast: 8 rows = 32768 elems
  {
    const size_t base = (size_t)b * 8 * D_IN;
#pragma unroll 4
    for (int c = 0; c < 16; ++c) {
      const size_t off = base + ((size_t)c * 256 + tid) * 8;
      cvt8(W + off, wb + off);
    }
  }
  // (3) y1 MFMA, K split across 4 waves
  const int wv = tid >> 6;
  const int lane = tid & 63;
  const int fr = lane & 15;
  const int fke = (lane >> 4) * 8;
  const int kw = wv * 1024;
  floatx4 acc = {0.f, 0.f, 0.f, 0.f};
  const float* ap = X + (size_t)(mb + fr) * D_IN + kw + fke;
  const float* rp = R + (size_t)fr * D_IN + kw + fke;
#pragma unroll 4
  for (int k = 0; k < 1024; k += 32) {
    const short8 av = cvt8r(ap + k);
    const short8 bv = cvt8r(rp + k);
    acc = __builtin_amdgcn_mfma_f32_16x16x32_bf16(av, bv, acc, 0, 0, 0);
  }
  *(floatx4*)&red[wv][lane * 4] = acc;
  __syncthreads();
  if (wv == 0) {
    floatx4 s = *(const floatx4*)&red[0][lane * 4];
    s += *(const floatx4*)&red[1][lane * 4];
    s += *(const floatx4*)&red[2][lane * 4];
    s += *(const floatx4*)&red[3][lane * 4];
    const int q = (lane >> 4) * 4;
#pragma unroll
    for (int r = 0; r < 4; ++r)
      y1b[(size_t)(mb + q + r) * 32 + fr] = f2bf(2.0f * s[r]);
    if (lane < 16) {
      const float4 z = make_float4(0.f, 0.f, 0.f, 0.f);
      *(float4*)(y1b + (size_t)(mb + lane) * 32 + 16) = z;
      *(float4*)(y1b + (size_t)(mb + lane) * 32 + 24) = z;
    }
  }
}

// ---------------------------------------------------------------------------
// gemm8 v4: C = A[M,K]bf16 * B[N,K]bf16^T (+ LoRA peel) + bias.
// Tile 128(M)x256(N), BK=32, 8 waves (2M x 4N), wave tile 64x64.
// acc[4][4] = 64 VGPR; __launch_bounds__(512,4) caps VGPR at 128 ->
// 4 waves/SIMD; LDS 48 KB -> 2 WGs/CU. Two INDEPENDENT workgroups per CU
// provide MFMA/LDS overlap via TLP (m114 mechanism) instead of the
// intra-WG schedule that measured strictly serial (R2/R3: wall/tile ==
// MFMA cy + LDS cy exactly).
// LDS: [rows][32k] 64-B rows; swizzle phys = log ^ (((log>>7)&3)<<4)
//   (involution: key bits 7-8 disjoint from target bits 4-5; frag reads
//    2-way max = free). Staging: linear dest, source slot perm
//    (t&3)^((t>>3)&3) -- same involution, coalesced within 64-B rows.
// Pipeline: stage(T+2) 2 tiles ahead (3 loads/tile), vmcnt(3) at tile end
//   (never 0 mid-loop); lgkmcnt(0)+barrier before staging into the live
//   buffer (WAR architecturally safe).
// ---------------------------------------------------------------------------
#define BMT 128
#define BNT 256
#define BK  32
#define BUFSZ 24576

#define SWZK(row) (((((row) >> 1) & 3)) << 4)

#define STG(KT, BUFOFF) do {                                                   \
    copy16(pa  + (size_t)(KT) * 32, smem + (BUFOFF) + tid * 16);               \
    copy16(pb0 + (size_t)(KT) * 32, smem + (BUFOFF) + 8192 + tid * 16);        \
    copy16(pb1 + (size_t)(KT) * 32, smem + (BUFOFF) + 16384 + tid * 16);       \
  } while (0)

#define ENDW3 do { asm volatile("s_waitcnt vmcnt(3)" ::: "memory");            \
    __builtin_amdgcn_sched_barrier(0); __builtin_amdgcn_s_barrier();           \
    asm volatile("" ::: "memory"); } while (0)
#define ENDW0 do { asm volatile("s_waitcnt vmcnt(0)" ::: "memory");            \
    __builtin_amdgcn_sched_barrier(0); __builtin_amdgcn_s_barrier();           \
    asm volatile("" ::: "memory"); } while (0)
#define ENDWN do { } while (0)

#define TILE(BUFOFF, T, SG, ENDW) do {                                         \
    short8 av[4], bv[4];                                                       \
    _Pragma("unroll")                                                          \
    for (int f_ = 0; f_ < 4; ++f_)                                             \
      av[f_] = *(const short8*)(smem + (BUFOFF) + pAb + f_ * 1024);            \
    _Pragma("unroll")                                                          \
    for (int f_ = 0; f_ < 4; ++f_)                                             \
      bv[f_] = *(const short8*)(smem + (BUFOFF) + pBb + f_ * 1024);            \
    asm volatile("s_waitcnt lgkmcnt(0)" ::: "memory");                         \
    __builtin_amdgcn_sched_barrier(0);                                         \
    __builtin_amdgcn_s_barrier();                                              \
    if (SG) STG((T) + 2, BUFOFF);                                              \
    __builtin_amdgcn_s_setprio(1);                                             \
    _Pragma("unroll")                                                          \
    for (int i_ = 0; i_ < 4; ++i_) {                                           \
      _Pragma("unroll")                                                        \
      for (int j_ = 0; j_ < 4; ++j_)                                           \
        acc[i_][j_] = __builtin_amdgcn_mfma_f32_16x16x32_bf16(                 \
            av[i_], bv[j_], acc[i_][j_], 0, 0, 0);                             \
    }                                                                          \
    __builtin_amdgcn_s_setprio(0);                                             \
    ENDW;                                                                      \
  } while (0)

__global__ __launch_bounds__(512, 4) void gemm8(
    const unsigned short* __restrict__ A,    // [NTOK, D_IN] bf16
    const unsigned short* __restrict__ B,    // [D_OUT, D_IN] bf16 (W cast)
    const float* __restrict__ bias,
    const unsigned short* __restrict__ y1b,  // [NTOK, 32] bf16 (cols 16-31 = 0)
    const float* __restrict__ L,             // [D_OUT, 16] fp32
    float* __restrict__ C) {                 // [NTOK, D_OUT] fp32
  __shared__ __align__(16) unsigned char smem[49152];

  const int tid = threadIdx.x;
  const int lane = tid & 63;
  const int w  = tid >> 6;
  const int wm = (w >> 2) * 64;
  const int wn = (w & 3) * 64;
  const int fr  = lane & 15;
  const int fkb = (lane >> 4) * 16;
  const int fke = (lane >> 4) * 8;

  // T1: bijective XCD swizzle (1024 WGs, %8==0). Per XCD: m-major chunk
  // of 128 blocks spanning 2 n-panels -> B panels L2-resident.
  const int bid  = blockIdx.x;
  const int swzb = (bid & 7) * 128 + (bid >> 3);
  const int m0 = (swzb & 63) * BMT;
  const int n0 = (swzb >> 6) * BNT;

  // staging source (swizzle-inverse): row t>>2, slot (t&3)^((t>>3)&3)
  const int srow = tid >> 2;
  const int scol = ((tid & 3) ^ ((tid >> 3) & 3)) * 8;
  const unsigned short* pa  = A + (size_t)(m0 + srow) * D_IN + scol;
  const unsigned short* pb0 = B + (size_t)(n0 + srow) * D_IN + scol;
  const unsigned short* pb1 = B + (size_t)(n0 + 128 + srow) * D_IN + scol;

  // ds_read physical bases (key (row>>1)&3 invariant under +16-row frags)
  const int rA = wm + fr;
  const int rB = wn + fr;
  const int pAb = (rA * 64 + fkb) ^ SWZK(rA);
  const int pBb = 8192 + ((rB * 64 + fkb) ^ SWZK(rB));

  floatx4 acc[4][4] = {};

  // prologue: stage T0 -> buf0, T1 -> buf1; wait T0 (3 of 6 in flight)
  STG(0, 0);
  STG(1, BUFSZ);
  asm volatile("s_waitcnt vmcnt(3)" ::: "memory");
  __builtin_amdgcn_s_barrier();

  // 128 K-tiles; stages run through T=125 (targets tile 127)
  for (int t2 = 0; t2 < 63; ++t2) {
    const int T = t2 * 2;
    TILE(0,     T,     true, ENDW3);
    TILE(BUFSZ, T + 1, true, ENDW3);
  }
  TILE(0,     126, false, ENDW0);
  TILE(BUFSZ, 127, false, ENDWN);

  // peeled rank-16 LoRA K-step: yav from y1b (bf16), lbv from L fp32
  // (in-register cvt; lanes with fke>=16 use the zero pad)
  {
    short8 lbv[4];
#pragma unroll
    for (int j = 0; j < 4; ++j) {
      if (fke < 16) {
        lbv[j] = cvt8r(L + (size_t)(n0 + wn + j * 16 + fr) * LORA_DIM + fke);
      } else {
        short8 z = {0, 0, 0, 0, 0, 0, 0, 0};
        lbv[j] = z;
      }
    }
#pragma unroll
    for (int i = 0; i < 4; ++i) {
      const short8 yav = *(const short8*)(y1b + (size_t)(m0 + wm + i * 16 + fr) * 32 + fke);
#pragma unroll
      for (int j = 0; j < 4; ++j)
        acc[i][j] = __builtin_amdgcn_mfma_f32_16x16x32_bf16(yav, lbv[j],
                                                            acc[i][j], 0, 0, 0);
    }
  }

  // epilogue: C/D layout col=lane&15, row=(lane>>4)*4+reg
  const int q4 = (lane >> 4) * 4;
#pragma unroll
  for (int j = 0; j < 4; ++j) {
    const int col = n0 + wn + j * 16 + fr;
    const float bs = bias[col];
#pragma unroll
    for (int i = 0; i < 4; ++i) {
      const size_t row = (size_t)(m0 + wm + i * 16 + q4);
      const floatx4 v = acc[i][j];
#pragma unroll
      for (int r = 0; r < 4; ++r)
        C[(row + r) * D_OUT + col] = v[r] + bs;
    }
  }
}

// ---------------------------------------------------------------------------
extern "C" void kernel_launch(void* const* d_in, const int* in_sizes, int n_in,
                              void* d_out, int out_size, void* d_ws, size_t ws_size,
                              hipStream_t stream) {
  const float* x    = (const float*)d_in[0];
  const float* W    = (const float*)d_in[1];
  const float* bias = (const float*)d_in[2];
  const float* L    = (const float*)d_in[3];
  const float* R    = (const float*)d_in[4];
  float* out = (float*)d_out;

  const size_t n_xb  = (size_t)NTOK * D_IN;
  const size_t n_wb  = (size_t)D_OUT * D_IN;
  const size_t n_y1b = (size_t)NTOK * 32;
  const size_t need = (n_xb + n_wb + n_y1b) * sizeof(unsigned short);
  if (ws_size < need) return;

  unsigned short* xb  = (unsigned short*)d_ws;
  unsigned short* wb  = xb + n_xb;
  unsigned short* y1b = wb + n_wb;

  prep2<<<512, 256, 0, stream>>>(x, W, R, xb, wb, y1b);
  gemm8<<<dim3((NTOK / BMT) * (D_OUT / BNT)), 512, 0, stream>>>(xb, wb, bias,
                                                                y1b, L, out);
}